// Round 1
// baseline (1497.040 us; speedup 1.0000x reference)
//
#include <hip/hip_runtime.h>

#define NN 100000
#define NE 1600000
#define DF 128
#define H  64

typedef __attribute__((ext_vector_type(8))) short bf16x8;
typedef __attribute__((ext_vector_type(4))) float f32x4;

#define MFMA(a, b, c) __builtin_amdgcn_mfma_f32_16x16x32_bf16((a), (b), (c), 0, 0, 0)

__device__ __forceinline__ short f2bf(float f) {
    unsigned u = __float_as_uint(f);
    u += 0x7fffu + ((u >> 16) & 1u);   // round-to-nearest-even (inputs are finite)
    return (short)(u >> 16);
}

// 8 consecutive floats -> 8 bf16 fragment (A or B operand of 16x16x32)
__device__ __forceinline__ bf16x8 load_frag8(const float* __restrict__ p) {
    const float4 x = *reinterpret_cast<const float4*>(p);
    const float4 y = *reinterpret_cast<const float4*>(p + 4);
    bf16x8 r;
    r[0] = f2bf(x.x); r[1] = f2bf(x.y); r[2] = f2bf(x.z); r[3] = f2bf(x.w);
    r[4] = f2bf(y.x); r[5] = f2bf(y.y); r[6] = f2bf(y.z); r[7] = f2bf(y.w);
    return r;
}

// ---------------------------------------------------------------------------
// node_proj[N,64] = node_feats[N,128] @ W_node[64,128]^T
// wave computes 16 rows x 64 cols; 4 n-tiles x 4 k-steps of mfma 16x16x32 bf16
// ---------------------------------------------------------------------------
__global__ void __launch_bounds__(256) proj_kernel(
    const float* __restrict__ feats, const float* __restrict__ W,
    float* __restrict__ out, int n_rows)
{
    const int lane = threadIdx.x & 63;
    const int q = lane >> 4, c = lane & 15;

    bf16x8 bfr[4][4];   // [n-tile][k-step]  B[k][n] = W[16t+c][32s+8q+j]
#pragma unroll
    for (int t = 0; t < 4; ++t)
#pragma unroll
        for (int s = 0; s < 4; ++s)
            bfr[t][s] = load_frag8(W + (16 * t + c) * 128 + 32 * s + 8 * q);

    const int wid = blockIdx.x * (blockDim.x >> 6) + (threadIdx.x >> 6);
    const int nw  = gridDim.x * (blockDim.x >> 6);
    const int ng  = n_rows >> 4;
    const f32x4 z4 = {0.f, 0.f, 0.f, 0.f};

    for (int g = wid; g < ng; g += nw) {
        const int r0 = g << 4;
        f32x4 acc[4];
#pragma unroll
        for (int t = 0; t < 4; ++t) acc[t] = z4;
#pragma unroll
        for (int s = 0; s < 4; ++s) {
            bf16x8 a = load_frag8(feats + (size_t)(r0 + c) * 128 + 32 * s + 8 * q);
#pragma unroll
            for (int t = 0; t < 4; ++t)
                acc[t] = MFMA(a, bfr[t][s], acc[t]);
        }
        // C: row = 4q+r, col = 16t+c
#pragma unroll
        for (int t = 0; t < 4; ++t)
#pragma unroll
            for (int r = 0; r < 4; ++r)
                out[(r0 + 4 * q + r) * 64 + 16 * t + c] = acc[t][r];
    }
}

// ---------------------------------------------------------------------------
// Fused edge pipeline: edge_proj -> +node_proj[src] -> softmax(dim=1)
//                      -> *node_hidden[src] -> atomicAdd h_new[dst]
// ---------------------------------------------------------------------------
__global__ void __launch_bounds__(256) edge_kernel(
    const float* __restrict__ edge_feats, const float* __restrict__ W_edge,
    const float* __restrict__ node_proj, const float* __restrict__ node_hidden,
    const int* __restrict__ src, const int* __restrict__ dst,
    float* __restrict__ h_new)
{
    const int lane = threadIdx.x & 63;
    const int q = lane >> 4, c = lane & 15;

    bf16x8 bfr[4][4];
#pragma unroll
    for (int t = 0; t < 4; ++t)
#pragma unroll
        for (int s = 0; s < 4; ++s)
            bfr[t][s] = load_frag8(W_edge + (16 * t + c) * 128 + 32 * s + 8 * q);

    const int wid = blockIdx.x * (blockDim.x >> 6) + (threadIdx.x >> 6);
    const int nw  = gridDim.x * (blockDim.x >> 6);
    const int ng  = NE >> 4;           // 100000, exact
    const f32x4 z4 = {0.f, 0.f, 0.f, 0.f};

    for (int g = wid; g < ng; g += nw) {
        const int e0 = g << 4;
        f32x4 acc[4];
#pragma unroll
        for (int t = 0; t < 4; ++t) acc[t] = z4;
#pragma unroll
        for (int s = 0; s < 4; ++s) {
            bf16x8 a = load_frag8(edge_feats + (size_t)(e0 + c) * 128 + 32 * s + 8 * q);
#pragma unroll
            for (int t = 0; t < 4; ++t)
                acc[t] = MFMA(a, bfr[t][s], acc[t]);
        }

        // this lane's 4 rows: e = e0 + 4q + r
        int sr[4], dr[4];
#pragma unroll
        for (int r = 0; r < 4; ++r) {
            const int e = e0 + 4 * q + r;
            sr[r] = src[e];
            dr[r] = dst[e];
        }

        // edge_msg = edge_proj + node_proj[src];  val[t][r], col = 16t+c
        float val[4][4];
#pragma unroll
        for (int t = 0; t < 4; ++t)
#pragma unroll
            for (int r = 0; r < 4; ++r)
                val[t][r] = acc[t][r] + node_proj[sr[r] * 64 + 16 * t + c];

        // per-row softmax over 64 cols: 4 regs x 16 quad-lanes
#pragma unroll
        for (int r = 0; r < 4; ++r) {
            float m = fmaxf(fmaxf(val[0][r], val[1][r]), fmaxf(val[2][r], val[3][r]));
#pragma unroll
            for (int msk = 1; msk < 16; msk <<= 1)
                m = fmaxf(m, __shfl_xor(m, msk));
            float sum = 0.f;
#pragma unroll
            for (int t = 0; t < 4; ++t) {
                val[t][r] = __expf(val[t][r] - m);
                sum += val[t][r];
            }
#pragma unroll
            for (int msk = 1; msk < 16; msk <<= 1)
                sum += __shfl_xor(sum, msk);
            const float inv = __fdividef(1.f, sum);
#pragma unroll
            for (int t = 0; t < 4; ++t) val[t][r] *= inv;
        }

        // m = alpha * node_hidden[src]; scatter-add to h_new[dst]
#pragma unroll
        for (int r = 0; r < 4; ++r) {
            const int sb = sr[r] * 64;
            const int db = dr[r] * 64;
#pragma unroll
            for (int t = 0; t < 4; ++t) {
                const float mv = val[t][r] * node_hidden[sb + 16 * t + c];
                atomicAdd(&h_new[db + 16 * t + c], mv);
            }
        }
    }
}

// ---------------------------------------------------------------------------
// GRU cell: gi = h_new@W_ih^T + b_ih, gh = hidden@W_hh^T + b_hh, gates, out.
// wave owns 16 nodes; per g in 0..3 computes col block 16g..16g+15 of all
// three gates (n-tiles g, g+4, g+8) for both GEMMs: 12 MFMA, then epilogue.
// ---------------------------------------------------------------------------
__global__ void __launch_bounds__(256) gru_kernel(
    const float* __restrict__ h_new, const float* __restrict__ hidden,
    const float* __restrict__ W_ih, const float* __restrict__ W_hh,
    const float* __restrict__ b_ih, const float* __restrict__ b_hh,
    float* __restrict__ out)
{
    const int lane = threadIdx.x & 63;
    const int q = lane >> 4, c = lane & 15;
    const int wid = blockIdx.x * (blockDim.x >> 6) + (threadIdx.x >> 6);
    const int nw  = gridDim.x * (blockDim.x >> 6);
    const int ng  = NN >> 4;           // 6250, exact
    const f32x4 z4 = {0.f, 0.f, 0.f, 0.f};

    for (int g = wid; g < ng; g += nw) {
        const int n0 = g << 4;
        bf16x8 ai[2], ah[2];           // A-frags, K=64 -> 2 k-steps
#pragma unroll
        for (int s = 0; s < 2; ++s) {
            ai[s] = load_frag8(h_new  + (n0 + c) * 64 + 32 * s + 8 * q);
            ah[s] = load_frag8(hidden + (n0 + c) * 64 + 32 * s + 8 * q);
        }
#pragma unroll
        for (int gg = 0; gg < 4; ++gg) {
            f32x4 ir = z4, iz = z4, inn = z4, hr = z4, hz = z4, hn = z4;
#pragma unroll
            for (int s = 0; s < 2; ++s) {
                const int ko = 32 * s + 8 * q;
                ir  = MFMA(ai[s], load_frag8(W_ih + (16 * gg       + c) * 64 + ko), ir);
                iz  = MFMA(ai[s], load_frag8(W_ih + (16 * (gg + 4) + c) * 64 + ko), iz);
                inn = MFMA(ai[s], load_frag8(W_ih + (16 * (gg + 8) + c) * 64 + ko), inn);
                hr  = MFMA(ah[s], load_frag8(W_hh + (16 * gg       + c) * 64 + ko), hr);
                hz  = MFMA(ah[s], load_frag8(W_hh + (16 * (gg + 4) + c) * 64 + ko), hz);
                hn  = MFMA(ah[s], load_frag8(W_hh + (16 * (gg + 8) + c) * 64 + ko), hn);
            }
            const int col = 16 * gg + c;
            const float bir = b_ih[col], biz = b_ih[64 + col], bin = b_ih[128 + col];
            const float bhr = b_hh[col], bhz = b_hh[64 + col], bhn = b_hh[128 + col];
#pragma unroll
            for (int r = 0; r < 4; ++r) {
                const int node = n0 + 4 * q + r;
                const float h  = hidden[node * 64 + col];
                const float rr = __fdividef(1.f, 1.f + __expf(-(ir[r] + bir + hr[r] + bhr)));
                const float zz = __fdividef(1.f, 1.f + __expf(-(iz[r] + biz + hz[r] + bhz)));
                const float x  = inn[r] + bin + rr * (hn[r] + bhn);
                const float nn = 1.f - __fdividef(2.f, __expf(2.f * x) + 1.f);   // tanh
                out[node * 64 + col] = (1.f - zz) * nn + zz * h;
            }
        }
    }
}

extern "C" void kernel_launch(void* const* d_in, const int* in_sizes, int n_in,
                              void* d_out, int out_size, void* d_ws, size_t ws_size,
                              hipStream_t stream) {
    const float* node_feats  = (const float*)d_in[0];
    const float* edge_feats  = (const float*)d_in[1];
    const float* node_hidden = (const float*)d_in[2];
    const int*   src         = (const int*)d_in[3];
    const int*   dst         = (const int*)d_in[4];
    const float* W_edge      = (const float*)d_in[5];
    const float* W_node      = (const float*)d_in[6];
    const float* W_ih        = (const float*)d_in[7];
    const float* W_hh        = (const float*)d_in[8];
    const float* b_ih        = (const float*)d_in[9];
    const float* b_hh        = (const float*)d_in[10];
    float* out = (float*)d_out;

    float* node_proj = (float*)d_ws;                       // 100000*64 f32 = 25.6 MB
    float* h_new     = node_proj + (size_t)NN * H;         // 100000*64 f32 = 25.6 MB

    // h_new must start at zero every launch (ws is re-poisoned to 0xAA)
    hipMemsetAsync(h_new, 0, (size_t)NN * H * sizeof(float), stream);

    proj_kernel<<<1563, 256, 0, stream>>>(node_feats, W_node, node_proj, NN);
    edge_kernel<<<4096, 256, 0, stream>>>(edge_feats, W_edge, node_proj, node_hidden,
                                          src, dst, h_new);
    gru_kernel<<<1563, 256, 0, stream>>>(h_new, node_hidden, W_ih, W_hh, b_ih, b_hh, out);
}

// Round 2
// 1458.745 us; speedup vs baseline: 1.0263x; 1.0263x over previous
//
#include <hip/hip_runtime.h>

#define NN 100000
#define NE 1600000
#define DF 128
#define H  64

typedef __attribute__((ext_vector_type(8))) short bf16x8;
typedef __attribute__((ext_vector_type(4))) float f32x4;

#define MFMA(a, b, c) __builtin_amdgcn_mfma_f32_16x16x32_bf16((a), (b), (c), 0, 0, 0)

__device__ __forceinline__ unsigned short f2bf(float f) {
    unsigned u = __float_as_uint(f);
    u += 0x7fffu + ((u >> 16) & 1u);   // round-to-nearest-even (inputs are finite)
    return (unsigned short)(u >> 16);
}

__device__ __forceinline__ float bf2f(unsigned short us) {
    return __uint_as_float((unsigned)us << 16);
}

// 8 consecutive floats -> 8 bf16 fragment (A or B operand of 16x16x32)
__device__ __forceinline__ bf16x8 load_frag8(const float* __restrict__ p) {
    const float4 x = *reinterpret_cast<const float4*>(p);
    const float4 y = *reinterpret_cast<const float4*>(p + 4);
    bf16x8 r;
    r[0] = f2bf(x.x); r[1] = f2bf(x.y); r[2] = f2bf(x.z); r[3] = f2bf(x.w);
    r[4] = f2bf(y.x); r[5] = f2bf(y.y); r[6] = f2bf(y.z); r[7] = f2bf(y.w);
    return r;
}

// packed bf16 atomic add (2 cols per op); addr must be 4B-aligned
__device__ __forceinline__ void atomic_pk_add_bf16(unsigned short* addr, unsigned data) {
    asm volatile("global_atomic_pk_add_bf16 %0, %1, off"
                 :: "v"((unsigned long long)(uintptr_t)addr), "v"(data)
                 : "memory");
}

// ---------------------------------------------------------------------------
// node_proj[N,64] = node_feats[N,128] @ W_node[64,128]^T  (f32 out)
// fused: convert node_hidden rows of this tile to bf16 table nh_bf
// ---------------------------------------------------------------------------
__global__ void __launch_bounds__(256) proj_kernel(
    const float* __restrict__ feats, const float* __restrict__ W,
    const float* __restrict__ hidden,
    float* __restrict__ out, unsigned short* __restrict__ nh_bf, int n_rows)
{
    const int lane = threadIdx.x & 63;
    const int q = lane >> 4, c = lane & 15;

    bf16x8 bfr[4][4];   // [n-tile][k-step]  B[k][n] = W[16t+c][32s+8q+j]
#pragma unroll
    for (int t = 0; t < 4; ++t)
#pragma unroll
        for (int s = 0; s < 4; ++s)
            bfr[t][s] = load_frag8(W + (16 * t + c) * 128 + 32 * s + 8 * q);

    const int wid = blockIdx.x * (blockDim.x >> 6) + (threadIdx.x >> 6);
    const int nw  = gridDim.x * (blockDim.x >> 6);
    const int ng  = n_rows >> 4;
    const f32x4 z4 = {0.f, 0.f, 0.f, 0.f};

    for (int g = wid; g < ng; g += nw) {
        const int r0 = g << 4;
        f32x4 acc[4];
#pragma unroll
        for (int t = 0; t < 4; ++t) acc[t] = z4;
#pragma unroll
        for (int s = 0; s < 4; ++s) {
            bf16x8 a = load_frag8(feats + (size_t)(r0 + c) * 128 + 32 * s + 8 * q);
#pragma unroll
            for (int t = 0; t < 4; ++t)
                acc[t] = MFMA(a, bfr[t][s], acc[t]);
        }
        // C: row = 4q+r, col = 16t+c
#pragma unroll
        for (int t = 0; t < 4; ++t)
#pragma unroll
            for (int r = 0; r < 4; ++r)
                out[(r0 + 4 * q + r) * 64 + 16 * t + c] = acc[t][r];

        // convert node_hidden tile to bf16: lane c handles cols 4c..4c+3
#pragma unroll
        for (int rr = 0; rr < 4; ++rr) {
            const int row = r0 + 4 * q + rr;
            const float4 v = *reinterpret_cast<const float4*>(hidden + row * 64 + 4 * c);
            uint2 pk;
            pk.x = (unsigned)f2bf(v.x) | ((unsigned)f2bf(v.y) << 16);
            pk.y = (unsigned)f2bf(v.z) | ((unsigned)f2bf(v.w) << 16);
            *reinterpret_cast<uint2*>(nh_bf + row * 64 + 4 * c) = pk;
        }
    }
}

// ---------------------------------------------------------------------------
// Fused edge pipeline: edge_proj -> +node_proj[src] -> softmax(dim=1)
//                      -> *nh_bf[src] -> pk-bf16 atomicAdd h_new[dst]
// ---------------------------------------------------------------------------
__global__ void __launch_bounds__(256) edge_kernel(
    const float* __restrict__ edge_feats, const float* __restrict__ W_edge,
    const float* __restrict__ node_proj, const unsigned short* __restrict__ nh_bf,
    const int* __restrict__ src, const int* __restrict__ dst,
    unsigned short* __restrict__ h_new)
{
    const int lane = threadIdx.x & 63;
    const int q = lane >> 4, c = lane & 15;
    const int par = lane & 1;          // lane pair parity (pairs are (c, c^1))

    bf16x8 bfr[4][4];
#pragma unroll
    for (int t = 0; t < 4; ++t)
#pragma unroll
        for (int s = 0; s < 4; ++s)
            bfr[t][s] = load_frag8(W_edge + (16 * t + c) * 128 + 32 * s + 8 * q);

    const int wid = blockIdx.x * (blockDim.x >> 6) + (threadIdx.x >> 6);
    const int nw  = gridDim.x * (blockDim.x >> 6);
    const int ng  = NE >> 4;           // 100000, exact
    const f32x4 z4 = {0.f, 0.f, 0.f, 0.f};

    for (int g = wid; g < ng; g += nw) {
        const int e0 = g << 4;
        f32x4 acc[4];
#pragma unroll
        for (int t = 0; t < 4; ++t) acc[t] = z4;
#pragma unroll
        for (int s = 0; s < 4; ++s) {
            bf16x8 a = load_frag8(edge_feats + (size_t)(e0 + c) * 128 + 32 * s + 8 * q);
#pragma unroll
            for (int t = 0; t < 4; ++t)
                acc[t] = MFMA(a, bfr[t][s], acc[t]);
        }

        // this lane's 4 rows: e = e0 + 4q + r
        int sr[4], dr[4];
#pragma unroll
        for (int r = 0; r < 4; ++r) {
            const int e = e0 + 4 * q + r;
            sr[r] = src[e];
            dr[r] = dst[e];
        }

        // edge_msg = edge_proj + node_proj[src];  val[t][r], col = 16t+c
        float val[4][4];
#pragma unroll
        for (int t = 0; t < 4; ++t)
#pragma unroll
            for (int r = 0; r < 4; ++r)
                val[t][r] = acc[t][r] + node_proj[sr[r] * 64 + 16 * t + c];

        // per-row softmax over 64 cols (4 regs x 16 quad-lanes)
#pragma unroll
        for (int r = 0; r < 4; ++r) {
            float m = fmaxf(fmaxf(val[0][r], val[1][r]), fmaxf(val[2][r], val[3][r]));
#pragma unroll
            for (int msk = 1; msk < 16; msk <<= 1)
                m = fmaxf(m, __shfl_xor(m, msk));
            float sum = 0.f;
#pragma unroll
            for (int t = 0; t < 4; ++t) {
                val[t][r] = __expf(val[t][r] - m);
                sum += val[t][r];
            }
#pragma unroll
            for (int msk = 1; msk < 16; msk <<= 1)
                sum += __shfl_xor(sum, msk);
            const float inv = __fdividef(1.f, sum);
#pragma unroll
            for (int t = 0; t < 4; ++t) val[t][r] *= inv;
        }

        // m = alpha * nh_bf[src] (bf16 gather), then packed-bf16 scatter-add.
        // Lane pair (c, c^1) covers cols (16t+2u, 16t+2u+1), u=c>>1.
        // Even lanes commit rows r=0,1; odd lanes rows r=2,3.
#pragma unroll
        for (int r = 0; r < 4; ++r) {
            const int sb = sr[r] * 64;
            const int db = dr[r] * 64 + (c & ~1);
            float mv[4];
#pragma unroll
            for (int t = 0; t < 4; ++t)
                mv[t] = val[t][r] * bf2f(nh_bf[sb + 16 * t + c]);
            const bool mine = par ? (r >= 2) : (r < 2);
#pragma unroll
            for (int t = 0; t < 4; ++t) {
                const float pv = __shfl_xor(mv[t], 1);   // uniform exchange
                if (mine) {
                    const float lo = par ? pv : mv[t];
                    const float hi = par ? mv[t] : pv;
                    const unsigned pk = (unsigned)f2bf(lo) | ((unsigned)f2bf(hi) << 16);
                    atomic_pk_add_bf16(h_new + db + 16 * t, pk);
                }
            }
        }
    }
    asm volatile("s_waitcnt vmcnt(0)" ::: "memory");   // drain atomics before endpgm
}

// ---------------------------------------------------------------------------
// GRU cell: gi = h_new@W_ih^T + b_ih, gh = hidden@W_hh^T + b_hh, gates, out.
// h_new is bf16 -> direct A-frag loads.
// ---------------------------------------------------------------------------
__global__ void __launch_bounds__(256) gru_kernel(
    const unsigned short* __restrict__ h_new, const float* __restrict__ hidden,
    const float* __restrict__ W_ih, const float* __restrict__ W_hh,
    const float* __restrict__ b_ih, const float* __restrict__ b_hh,
    float* __restrict__ out)
{
    const int lane = threadIdx.x & 63;
    const int q = lane >> 4, c = lane & 15;
    const int wid = blockIdx.x * (blockDim.x >> 6) + (threadIdx.x >> 6);
    const int nw  = gridDim.x * (blockDim.x >> 6);
    const int ng  = NN >> 4;           // 6250, exact
    const f32x4 z4 = {0.f, 0.f, 0.f, 0.f};

    for (int g = wid; g < ng; g += nw) {
        const int n0 = g << 4;
        bf16x8 ai[2], ah[2];           // A-frags, K=64 -> 2 k-steps
#pragma unroll
        for (int s = 0; s < 2; ++s) {
            ai[s] = *reinterpret_cast<const bf16x8*>(h_new + (n0 + c) * 64 + 32 * s + 8 * q);
            ah[s] = load_frag8(hidden + (n0 + c) * 64 + 32 * s + 8 * q);
        }
#pragma unroll
        for (int gg = 0; gg < 4; ++gg) {
            f32x4 ir = z4, iz = z4, inn = z4, hr = z4, hz = z4, hn = z4;
#pragma unroll
            for (int s = 0; s < 2; ++s) {
                const int ko = 32 * s + 8 * q;
                ir  = MFMA(ai[s], load_frag8(W_ih + (16 * gg       + c) * 64 + ko), ir);
                iz  = MFMA(ai[s], load_frag8(W_ih + (16 * (gg + 4) + c) * 64 + ko), iz);
                inn = MFMA(ai[s], load_frag8(W_ih + (16 * (gg + 8) + c) * 64 + ko), inn);
                hr  = MFMA(ah[s], load_frag8(W_hh + (16 * gg       + c) * 64 + ko), hr);
                hz  = MFMA(ah[s], load_frag8(W_hh + (16 * (gg + 4) + c) * 64 + ko), hz);
                hn  = MFMA(ah[s], load_frag8(W_hh + (16 * (gg + 8) + c) * 64 + ko), hn);
            }
            const int col = 16 * gg + c;
            const float bir = b_ih[col], biz = b_ih[64 + col], bin = b_ih[128 + col];
            const float bhr = b_hh[col], bhz = b_hh[64 + col], bhn = b_hh[128 + col];
#pragma unroll
            for (int r = 0; r < 4; ++r) {
                const int node = n0 + 4 * q + r;
                const float h  = hidden[node * 64 + col];
                const float rr = __fdividef(1.f, 1.f + __expf(-(ir[r] + bir + hr[r] + bhr)));
                const float zz = __fdividef(1.f, 1.f + __expf(-(iz[r] + biz + hz[r] + bhz)));
                const float x  = inn[r] + bin + rr * (hn[r] + bhn);
                const float nn = 1.f - __fdividef(2.f, __expf(2.f * x) + 1.f);   // tanh
                out[node * 64 + col] = (1.f - zz) * nn + zz * h;
            }
        }
    }
}

extern "C" void kernel_launch(void* const* d_in, const int* in_sizes, int n_in,
                              void* d_out, int out_size, void* d_ws, size_t ws_size,
                              hipStream_t stream) {
    const float* node_feats  = (const float*)d_in[0];
    const float* edge_feats  = (const float*)d_in[1];
    const float* node_hidden = (const float*)d_in[2];
    const int*   src         = (const int*)d_in[3];
    const int*   dst         = (const int*)d_in[4];
    const float* W_edge      = (const float*)d_in[5];
    const float* W_node      = (const float*)d_in[6];
    const float* W_ih        = (const float*)d_in[7];
    const float* W_hh        = (const float*)d_in[8];
    const float* b_ih        = (const float*)d_in[9];
    const float* b_hh        = (const float*)d_in[10];
    float* out = (float*)d_out;

    float*          node_proj = (float*)d_ws;                               // 25.6 MB
    unsigned short* nh_bf     = (unsigned short*)(node_proj + (size_t)NN * H); // 12.8 MB
    unsigned short* h_new     = nh_bf + (size_t)NN * H;                     // 12.8 MB

    // h_new (bf16) must start at zero every launch (ws is re-poisoned to 0xAA)
    hipMemsetAsync(h_new, 0, (size_t)NN * H * sizeof(unsigned short), stream);

    proj_kernel<<<1563, 256, 0, stream>>>(node_feats, W_node, node_hidden,
                                          node_proj, nh_bf, NN);
    edge_kernel<<<4096, 256, 0, stream>>>(edge_feats, W_edge, node_proj, nh_bf,
                                          src, dst, h_new);
    gru_kernel<<<1563, 256, 0, stream>>>(h_new, node_hidden, W_ih, W_hh, b_ih, b_hh, out);
}